// Round 4
// baseline (15509.871 us; speedup 1.0000x reference)
//
#include <hip/hip_runtime.h>

#define NROW 2000
#define NB   16
#define NT   24
#define NH   64
#define NM   (NROW*NB)          // 32000 flat rows (n*16+b)
#define HOPLDS (NROW*64)        // 128000 B dynamic LDS (stride 64: full-bank-coverage rows)
#define ENT_CAP 262144

typedef _Float16 h16;
typedef __attribute__((ext_vector_type(2))) _Float16 h16x2;
typedef __attribute__((ext_vector_type(8))) _Float16 h16x8;
typedef __attribute__((ext_vector_type(4))) float    f32x4;

__device__ __forceinline__ h16x2 bc_h2(unsigned int u){ union{unsigned int u; h16x2 h;} c; c.u=u; return c.h; }

// ---------------------------------------------------------------- CSR build
__global__ __launch_bounds__(256) void k_count(const float* adj, int* cnt_q, int* cnt_h, int* cnt_ns,
    float* rsum_q, float* rsum_h, float* rsum_ns, int* deg_ns){
  int wid = (blockIdx.x*256 + threadIdx.x)>>6;
  int lane = threadIdx.x & 63;
  int kind = wid / NROW, n = wid - kind*NROW;
  int cnt = 0; float sum = 0.f;
  for (int c = lane; c < NROW; c += 64){
    float v = (kind==1) ? adj[(size_t)c*NROW + n] : adj[(size_t)n*NROW + c];
    if (kind==2 && c==n) v = 0.f;
    cnt += (v != 0.f); sum += v;
  }
  for (int off=32; off; off>>=1){ cnt += __shfl_down(cnt,off); sum += __shfl_down(sum,off); }
  if (lane==0){
    int pc = (cnt+7)&~7;                       // pad rows to multiple of 8 entries
    if (kind==0){ cnt_q[n]=pc; rsum_q[n]=sum; }
    else if (kind==1){ cnt_h[n]=pc; rsum_h[n]=sum; }
    else { cnt_ns[n]=pc; rsum_ns[n]=sum; deg_ns[n]=cnt; }
  }
}

__global__ __launch_bounds__(1024) void k_scan(const int* cq, const int* ch, const int* cn,
    int* rq, int* rh, int* rn){
  __shared__ int s0[2048], s1[2048], s2[2048];
  int t = threadIdx.x;
  for (int a=0;a<2;a++){ int i=t+a*1024; s0[i]= i<NROW?cq[i]:0; s1[i]= i<NROW?ch[i]:0; s2[i]= i<NROW?cn[i]:0; }
  __syncthreads();
  for (int off=1; off<2048; off<<=1){
    int v0[2],v1[2],v2[2];
    for (int a=0;a<2;a++){ int i=t+a*1024; v0[a]= i>=off? s0[i-off]:0; v1[a]= i>=off? s1[i-off]:0; v2[a]= i>=off? s2[i-off]:0; }
    __syncthreads();
    for (int a=0;a<2;a++){ int i=t+a*1024; s0[i]+=v0[a]; s1[i]+=v1[a]; s2[i]+=v2[a]; }
    __syncthreads();
  }
  for (int a=0;a<2;a++){ int i=t+a*1024; if (i<=NROW){ rq[i]= i? s0[i-1]:0; rh[i]= i? s1[i-1]:0; rn[i]= i? s2[i-1]:0; } }
}

// degree-bucket counting sort: rows grouped by padded cnt (16-entry bins) so
// same-wave rows in k_hop have ~equal trip counts. Scatter order within a bin
// is atomic-order-dependent but numerics are row-independent -> output exact.
__global__ __launch_bounds__(1024) void k_sort(const int* c0, const int* c1, const int* c2,
                                               int* o0, int* o1, int* o2){
  const int* cnt = blockIdx.x==0 ? c0 : blockIdx.x==1 ? c1 : c2;
  int* order     = blockIdx.x==0 ? o0 : blockIdx.x==1 ? o1 : o2;
  __shared__ int hist[256];
  __shared__ int offs[256];
  int tid = threadIdx.x;
  if (tid < 256) hist[tid] = 0;
  __syncthreads();
  for (int r = tid; r < NROW; r += 1024){
    int b = cnt[r] >> 4; if (b > 255) b = 255;
    atomicAdd(&hist[b], 1);
  }
  __syncthreads();
  if (tid == 0){ int s = 0; for (int i=0;i<256;i++){ offs[i] = s; s += hist[i]; } }
  __syncthreads();
  for (int r = tid; r < NROW; r += 1024){
    int b = cnt[r] >> 4; if (b > 255) b = 255;
    int p = atomicAdd(&offs[b], 1);
    order[p] = r;
  }
}

__device__ __forceinline__ uint2 mk_ent(int c, float a){
  h16 h = (h16)a;
  unsigned short us = __builtin_bit_cast(unsigned short, h);
  return make_uint2((unsigned int)(c*64), (unsigned int)us * 0x10001u);
}

__global__ __launch_bounds__(256) void k_fill(const float* adj, const int* rptr_q, const int* rptr_h, const int* rptr_ns,
    const float* rsum_q, const float* rsum_h, const float* rsum_ns, const int* deg_ns,
    uint2* ent_q, uint2* ent_h, uint2* ent_m, uint2* ent_w){
  int wid = (blockIdx.x*256 + threadIdx.x)>>6;
  int lane = threadIdx.x & 63;
  int kind = wid / NROW, n = wid - kind*NROW;
  const int* rp = (kind==0)?rptr_q:(kind==1)?rptr_h:rptr_ns;
  int p = rp[n], pend = rp[n+1];
  float inv, invm = 0.f;
  if (kind==0){ float d = rsum_q[n]; inv = d!=0.f?1.f/d:0.f; }
  else if (kind==1){ float d = rsum_h[n]; inv = d!=0.f?1.f/d:0.f; }
  else { float d = rsum_ns[n]; inv = d!=0.f?1.f/d:0.f; int dg = deg_ns[n]; invm = 1.f/(float)(dg>1?dg:1); }
  int base = 0;
  unsigned long long below = (1ull<<lane)-1ull;
  for (int c0=0; c0<NROW; c0+=64){
    int c = c0+lane; float v = 0.f;
    if (c < NROW){ v = (kind==1)? adj[(size_t)c*NROW+n] : adj[(size_t)n*NROW+c]; if (kind==2 && c==n) v = 0.f; }
    unsigned long long m = __ballot(v != 0.f);
    if (v != 0.f){
      int pos = p + base + __popcll(m & below);
      if (kind==2){ ent_w[pos] = mk_ent(c, v*inv); ent_m[pos] = mk_ent(c, invm); }
      else if (kind==0) ent_q[pos] = mk_ent(c, v*inv);
      else              ent_h[pos] = mk_ent(c, v*inv);
    }
    base += __popcll(m);
  }
  for (int i = p+base+lane; i < pend; i += 64){
    uint2 z = make_uint2(0u,0u);
    if (kind==2){ ent_w[i]=z; ent_m[i]=z; } else if (kind==0) ent_q[i]=z; else ent_h[i]=z;
  }
}

// ---------------------------------------------------------------- sparse hop (SpMM), LDS-staged
// 1024 threads, 4-lane groups, ds_read_b128, row stride 64B. Degree-sorted row
// order (equal trip counts per wave) + rsplit-interleaved units (block balance).
struct HopJob { const h16* X; const int* rptr; const uint2* ent; const int* order; h16* out; };

__device__ __forceinline__ void proc2(const char* xs, int cl, uint4 p, h16x2 ha[4]){
  union{f32x4 v; h16x2 h[4];} ca, cb;
  ca.v = *(const f32x4*)(xs + p.x + cl);
  cb.v = *(const f32x4*)(xs + p.z + cl);
  h16x2 va = bc_h2(p.y), vb = bc_h2(p.w);
  ha[0] = ca.h[0]*va + ha[0];
  ha[1] = ca.h[1]*va + ha[1];
  ha[2] = ca.h[2]*va + ha[2];
  ha[3] = ca.h[3]*va + ha[3];
  ha[0] = cb.h[0]*vb + ha[0];
  ha[1] = cb.h[1]*vb + ha[1];
  ha[2] = cb.h[2]*vb + ha[2];
  ha[3] = cb.h[3]*vb + ha[3];
}

__global__ __launch_bounds__(1024) void k_hop(HopJob j0, HopJob j1, HopJob j2, HopJob j3,
                                              int coltiles, int rsplit, int C){
  extern __shared__ char xs[];
  int per = coltiles*rsplit;
  int bid = blockIdx.x;
  int jb = bid/per, rem = bid - jb*per;
  int ct = rem/rsplit, rs = rem - ct*rsplit;
  HopJob j = (jb==0)?j0:(jb==1)?j1:(jb==2)?j2:j3;
  int c0 = ct*32;
  int tid = threadIdx.x;
  { // stage X[:, c0..c0+31] fp16 into LDS, row stride 64B (conflict-free writes)
    int r0 = tid>>2, so = tid&3;
    const char* src = (const char*)j.X + (size_t)2*(c0 + so*8);
    char* dst = xs + so*16;
    for (int r = r0; r < NROW; r += 256)
      *(f32x4*)(dst + r*64) = *(const f32x4*)(src + (size_t)2*r*C);
  }
  __syncthreads();
  int lane = tid&63, wv = tid>>6;           // 16 waves
  int g = lane>>2;                          // 16 groups of 4 lanes
  int cl = (lane&3)*16;                     // 16B (8 cols) per lane
  // units: 125 units of 16 sorted rows; block rs takes units gu = rs + k*rsplit
  for (int k = wv; ; k += 16){
    int gu = rs + k*rsplit;
    if (gu >= 125) break;
    int n = j.order[gu*16 + g];
    {
      int p0 = j.rptr[n], cnt = j.rptr[n+1]-p0;
      const uint4* ep4 = (const uint4*)(j.ent + p0);   // 2 entries per uint4
      float f[8] = {0.f,0.f,0.f,0.f,0.f,0.f,0.f,0.f};
      if (cnt > 0){
        uint4 cur[8];
        #pragma unroll
        for (int u2=0;u2<8;u2++) cur[u2] = ep4[u2];    // 16 entries (overread garbage-safe)
        int i = 0;
        for (; i+16 <= cnt; i += 16){
          uint4 nx[8];
          int b = (i>>1)+8;
          #pragma unroll
          for (int u2=0;u2<8;u2++) nx[u2] = ep4[b+u2]; // next 16, issued before compute
          h16x2 ha[4] = {{(_Float16)0.f,(_Float16)0.f},{(_Float16)0.f,(_Float16)0.f},
                         {(_Float16)0.f,(_Float16)0.f},{(_Float16)0.f,(_Float16)0.f}};
          #pragma unroll
          for (int u2=0;u2<8;u2++) proc2(xs, cl, cur[u2], ha);
          f[0] += (float)ha[0][0]; f[1] += (float)ha[0][1];
          f[2] += (float)ha[1][0]; f[3] += (float)ha[1][1];
          f[4] += (float)ha[2][0]; f[5] += (float)ha[2][1];
          f[6] += (float)ha[3][0]; f[7] += (float)ha[3][1];
          #pragma unroll
          for (int u2=0;u2<8;u2++) cur[u2] = nx[u2];
        }
        if (i < cnt){                                   // tail of 8 (cnt % 16 == 8)
          h16x2 ha[4] = {{(_Float16)0.f,(_Float16)0.f},{(_Float16)0.f,(_Float16)0.f},
                         {(_Float16)0.f,(_Float16)0.f},{(_Float16)0.f,(_Float16)0.f}};
          proc2(xs, cl, cur[0], ha);
          proc2(xs, cl, cur[1], ha);
          proc2(xs, cl, cur[2], ha);
          proc2(xs, cl, cur[3], ha);
          f[0] += (float)ha[0][0]; f[1] += (float)ha[0][1];
          f[2] += (float)ha[1][0]; f[3] += (float)ha[1][1];
          f[4] += (float)ha[2][0]; f[5] += (float)ha[2][1];
          f[6] += (float)ha[3][0]; f[7] += (float)ha[3][1];
        }
      }
      alignas(16) h16 ov[8];
      #pragma unroll
      for (int k2=0;k2<8;k2++) ov[k2] = (h16)f[k2];
      *(uint4*)((char*)j.out + (size_t)2*((size_t)n*C + c0) + cl) = *(const uint4*)ov;
    }
  }
}

// ---------------------------------------------------------------- misc small kernels
__global__ void k_evinit(const float* rq, const float* rh, float* eq, float* eh){
  int n = blockIdx.x*256+threadIdx.x; if (n>=NROW) return;
  eq[n] = rq[n]!=0.f?1.f:0.f; eh[n] = rh[n]!=0.f?1.f:0.f;
}

__global__ __launch_bounds__(256) void k_matvec(const int* rptr, const uint2* ent, const float* vin, float* vout){
  int wid = (blockIdx.x*256+threadIdx.x)>>6; int lane = threadIdx.x&63;
  if (wid >= NROW) return;
  int p0 = rptr[wid], p1 = rptr[wid+1];
  float s = 0.f;
  for (int i=p0+lane; i<p1; i+=64){
    uint2 e = ent[i];
    int idx = (int)(e.x>>6);
    h16 hv = __builtin_bit_cast(h16, (unsigned short)(e.y & 0xffffu));
    s += (float)hv * vin[idx];
  }
  for (int off=32; off; off>>=1) s += __shfl_down(s,off);
  if (lane==0) vout[wid] = s;
}

__global__ void k_bias2(const float* W, const float* fcb, const float* e1, const float* e2,
                        const float* e3, const float* e4, float* dst, int O){
  int idx = blockIdx.x*256+threadIdx.x; if (idx >= NROW*O) return;
  int n = idx/O, o = idx - n*O;
  float v = W[o] + e1[n]*W[(size_t)65*O+o] + e2[n]*W[(size_t)130*O+o]
                 + e3[n]*W[(size_t)195*O+o] + e4[n]*W[(size_t)260*O+o];
  dst[idx] = fcb[0]*v;
}

// wpack: fp16 transposed W chunks [ch][O][32] for MFMA B-operand
__global__ void k_wpack(const float* W, const float* fcw, h16* dst, int O, int nch, int mode){
  int idx = blockIdx.x*256+threadIdx.x; if (idx >= nch*O*32) return;
  int k = idx&31; int o = (idx>>5)%O; int ch = idx/(O*32);
  float v = 0.f;
  if (mode==0){            // L0 enc-style: ch0-9 h-rows, ch10 x-rows
    if (ch < 10){ int m = ch>>1, j = (ch&1)*32 + k; v = W[(size_t)(m*65+1+j)*O + o]; }
    else if (k < 5) v = W[(size_t)(k*65)*O + o];
  } else if (mode==1){     // L1: ch 4m+s, j = (ch&3)*32+k
    int m = ch>>2, j = (ch&3)*32 + k; v = W[(size_t)(m*128+j)*O + o];
  } else {                 // L0 dec W'-style: ch0-9 = fcw[j]*W[m*65,o], ch10-19 h-rows
    if (ch < 10){ int m = ch>>1, j = (ch&1)*32 + k; v = fcw[j]*W[(size_t)(m*65)*O + o]; }
    else { int c2 = ch-10; int m = c2>>1, j = (c2&1)*32 + k; v = W[(size_t)(m*65+1+j)*O + o]; }
  }
  dst[(size_t)(ch*O + o)*32 + k] = (h16)v;
}

// ---------------------------------------------------------------- imputation
__global__ __launch_bounds__(256) void k_impute_gate(const float* x_enc, const float* gw1, const float* gb1,
    const float* gw2, const float* gb2, float* gate3, h16* xT){
  int tid = blockIdx.x*256+threadIdx.x; if (tid >= NM) return;
  int b = tid / NROW, n = tid - b*NROW;
  float x24[NT];
  #pragma unroll
  for (int t=0;t<NT;t++) x24[t] = x_enc[((size_t)b*NT+t)*NROW + n];
  float acc[NH];
  #pragma unroll
  for (int h=0;h<NH;h++) acc[h] = gb1[h];
  for (int t=0;t<NT;t++){
    float xv = x24[t];
    #pragma unroll
    for (int h=0;h<NH;h++) acc[h] = fmaf(xv, gw1[t*NH+h], acc[h]);
  }
  #pragma unroll
  for (int h=0;h<NH;h++) acc[h] = fmaxf(acc[h], 0.f);
  float lg[3];
  #pragma unroll
  for (int e=0;e<3;e++){
    float s = gb2[e];
    #pragma unroll
    for (int h=0;h<NH;h++) s = fmaf(acc[h], gw2[h*3+e], s);
    lg[e] = s;
  }
  int i0 = 0; if (lg[1] > lg[0]) i0 = 1; if (lg[2] > lg[i0]) i0 = 2;
  int i1 = (i0==0)?1:0;
  for (int e=0;e<3;e++) if (e!=i0 && e!=i1 && lg[e] > lg[i1]) i1 = e;
  float w1 = expf(lg[i1]-lg[i0]);
  float s = 1.f + w1;
  float g[3] = {0.f,0.f,0.f};
  g[i0] = 1.f/s; g[i1] = w1/s;
  gate3[tid*3+0]=g[0]; gate3[tid*3+1]=g[1]; gate3[tid*3+2]=g[2];
  h16* xp = xT + ((size_t)n*NB + b)*NT;
  #pragma unroll
  for (int t=0;t<NT;t++) xp[t] = (h16)x24[t];
}

__global__ __launch_bounds__(256) void k_impute_combine(const float* x_enc, const h16* Zm, const h16* Zw,
    const float* gate3, const float* ewm, const float* ebm, const float* eww, const float* ebw,
    const float* ewd, const float* ebd, h16* ximp){
  int tid = blockIdx.x*256+threadIdx.x; if (tid >= NM) return;
  int b = tid / NROW, n = tid - b*NROW;
  float x24[NT], zm[NT], zw[NT];
  const h16* zp1 = Zm + ((size_t)n*NB+b)*NT;
  const h16* zp2 = Zw + ((size_t)n*NB+b)*NT;
  #pragma unroll
  for (int t=0;t<NT;t++){ x24[t] = x_enc[((size_t)b*NT+t)*NROW + n]; zm[t]=(float)zp1[t]; zw[t]=(float)zp2[t]; }
  float g0=gate3[tid*3], g1=gate3[tid*3+1], g2=gate3[tid*3+2];
  h16* op = ximp + ((size_t)n*NB+b)*NT;
  for (int t=0;t<NT;t++){
    float am=ebm[t], aw=ebw[t], ad=ebd[t];
    #pragma unroll
    for (int ss=0;ss<NT;ss++){ am = fmaf(zm[ss], ewm[ss*NT+t], am); aw = fmaf(zw[ss], eww[ss*NT+t], aw); ad = fmaf(zw[ss], ewd[ss*NT+t], ad); }
    float comb = g0*am + g1*aw + g2*ad;
    op[t] = (h16)((x24[t]==0.f)? comb : x24[t]);
  }
}

__global__ void k_xpack8(const h16* ximp, const h16* xq1, const h16* xq2, const h16* xh1, const h16* xh2, h16* xp){
  int idx = blockIdx.x*256+threadIdx.x; if (idx >= NT*NM) return;
  int t = idx/NM, r = idx - t*NM;
  size_t s = (size_t)r*NT + t;
  alignas(16) h16 v[8] = { ximp[s], xq1[s], xq2[s], xh1[s], xh2[s], (h16)0.f,(h16)0.f,(h16)0.f };
  *(uint4*)(xp + ((size_t)t*NM + r)*8) = *(const uint4*)v;
}

// ---------------------------------------------------------------- MFMA combine GEMM + fused cell epilogue
// LDS-free: wave w owns cols [w*O/4, (w+1)*O/4); A and B frags load global->VGPR
// (wpack frag reads are contiguous 1KB per wave); paired named-reg prefetch; no barriers.
struct GArgs {
  const h16* src[20];
  int rstrideB[20];
  int coffB[20];
  const h16* wpack;
  const float* bias;
  const h16* hbuf;
  h16* rhbuf;
  float* ubuf;
  h16* hout;
  const float* bias2;
  const float* fcw;
  const float* fcb;
  float* dout;
  int tstep;
  int nchunks;
  int xchunk;
};

template<int O, int GATE, int BIAS2, int FCOUT>
__global__ __launch_bounds__(256) void k_g(GArgs a){
  __shared__ float fcred[64*4];        // used only when FCOUT
  const int tid = threadIdx.x;
  const int lane = tid&63, wv = tid>>6;
  const int l15 = lane&15, l4 = lane>>4;
  const int mbase = blockIdx.x*64;
  const int cbase = wv*(O/4);
  constexpr int NCF = O/64;            // colfrags per wave (2 for O=128, 1 for O=64)
  f32x4 acc[4][NCF];
  #pragma unroll
  for (int rf=0;rf<4;rf++)
    #pragma unroll
    for (int cf=0;cf<NCF;cf++) acc[rf][cf] = (f32x4){0.f,0.f,0.f,0.f};

  h16x8 afA[4], bfA[NCF], afB[4], bfB[NCF];
  const h16x8 hz = {(_Float16)0.f,(_Float16)0.f,(_Float16)0.f,(_Float16)0.f,
                    (_Float16)0.f,(_Float16)0.f,(_Float16)0.f,(_Float16)0.f};

  auto loadCh = [&](int ch, h16x8 (&af)[4], h16x8 (&bf)[NCF]){
    const char* sp = (const char*)a.src[ch] + a.coffB[ch];
    if (ch == a.xchunk){
      #pragma unroll
      for (int rf=0; rf<4; rf++){
        int row = mbase + rf*16 + l15;
        af[rf] = (l4==0) ? *(const h16x8*)(sp + (size_t)row*16) : hz;
      }
    } else {
      int rs = a.rstrideB[ch];
      #pragma unroll
      for (int rf=0; rf<4; rf++){
        int row = mbase + rf*16 + l15;
        af[rf] = *(const h16x8*)(sp + (size_t)row*rs + l4*16);
      }
    }
    const char* wp = (const char*)a.wpack + (size_t)ch*O*64;
    #pragma unroll
    for (int cf=0; cf<NCF; cf++)
      bf[cf] = *(const h16x8*)(wp + (size_t)(cbase + cf*16 + l15)*64 + l4*16);
  };
  auto domfma = [&](h16x8 (&af)[4], h16x8 (&bf)[NCF]){
    #pragma unroll
    for (int rf=0; rf<4; rf++)
      #pragma unroll
      for (int cf=0; cf<NCF; cf++)
        acc[rf][cf] = __builtin_amdgcn_mfma_f32_16x16x32_f16(af[rf], bf[cf], acc[rf][cf], 0,0,0);
  };

  loadCh(0, afA, bfA);
  for (int ch=0; ch<a.nchunks; ch+=2){
    if (ch+1 < a.nchunks) loadCh(ch+1, afB, bfB);
    domfma(afA, bfA);
    if (ch+2 < a.nchunks) loadCh(ch+2, afA, bfA);
    if (ch+1 < a.nchunks) domfma(afB, bfB);
  }

  float fcp[16];
  #pragma unroll
  for (int k=0;k<16;k++) fcp[k]=0.f;
  #pragma unroll
  for (int rf=0; rf<4; rf++){
    #pragma unroll
    for (int cf=0; cf<NCF; cf++){
      #pragma unroll
      for (int i=0;i<4;i++){
        int row = mbase + rf*16 + l4*4 + i;
        int col = cbase + cf*16 + l15;
        float v = acc[rf][cf][i] + a.bias[col];
        if (BIAS2) v += a.bias2[(size_t)(row>>4)*O + col];
        if (GATE){
          float sg = 1.f/(1.f+expf(-v));
          if (cbase + cf*16 < NH){                      // r half
            float hv = (float)a.hbuf[(size_t)row*NH + col];
            a.rhbuf[(size_t)row*NH + col] = (h16)(sg*hv);
          } else {                                      // u half
            a.ubuf[(size_t)row*NH + (col-NH)] = sg;
          }
        } else {
          float cc = tanhf(v);
          float u  = a.ubuf[(size_t)row*NH + col];
          float hv = (float)a.hbuf[(size_t)row*NH + col];
          float hn = u*hv + (1.f-u)*cc;
          a.hout[(size_t)row*NH + col] = (h16)hn;
          if (FCOUT) fcp[rf*4+i] += hn * a.fcw[col];
        }
      }
    }
  }
  if (FCOUT){
    #pragma unroll
    for (int k=0;k<16;k++){
      float s = fcp[k];
      s += __shfl_xor(s,1); s += __shfl_xor(s,2); s += __shfl_xor(s,4); s += __shfl_xor(s,8);
      if (l15==0){
        int rf = k>>2, i = k&3;
        int row = rf*16 + l4*4 + i;                    // block-local row
        fcred[row*4 + wv] = s;
      }
    }
    __syncthreads();
    if (tid < 64){
      float s = fcred[tid*4] + fcred[tid*4+1] + fcred[tid*4+2] + fcred[tid*4+3];
      int row = mbase + tid;
      int n = row>>4, b = row&15;
      a.dout[(size_t)b*(NT*NROW) + (size_t)a.tstep*NROW + n] = s + a.fcb[0];
    }
  }
}

// ---------------------------------------------------------------- host
extern "C" void kernel_launch(void* const* d_in, const int* in_sizes, int n_in,
                              void* d_out, int out_size, void* d_ws, size_t ws_size,
                              hipStream_t stream)
{
  const float* adj   = (const float*)d_in[0];
  const float* x_enc = (const float*)d_in[1];
  const float* gw1   = (const float*)d_in[3];
  const float* gb1   = (const float*)d_in[4];
  const float* gw2   = (const float*)d_in[5];
  const float* gb2   = (const float*)d_in[6];
  const float* ewm   = (const float*)d_in[7];
  const float* ebm   = (const float*)d_in[8];
  const float* eww   = (const float*)d_in[9];
  const float* ebw   = (const float*)d_in[10];
  const float* ewd   = (const float*)d_in[11];
  const float* ebd   = (const float*)d_in[12];
  const float* Wg[4] = {(const float*)d_in[13],(const float*)d_in[17],(const float*)d_in[21],(const float*)d_in[25]};
  const float* bg[4] = {(const float*)d_in[14],(const float*)d_in[18],(const float*)d_in[22],(const float*)d_in[26]};
  const float* Wc[4] = {(const float*)d_in[15],(const float*)d_in[19],(const float*)d_in[23],(const float*)d_in[27]};
  const float* bc[4] = {(const float*)d_in[16],(const float*)d_in[20],(const float*)d_in[24],(const float*)d_in[28]};
  const float* fcw   = (const float*)d_in[29];
  const float* fcb   = (const float*)d_in[30];
  float* outp = (float*)d_out;
  (void)in_sizes; (void)n_in; (void)out_size; (void)ws_size;

  char* base = (char*)d_ws;
  size_t off = 0;
  auto alloc = [&](size_t sz)->char*{ char* p = base + off; off += (sz + 255) & ~(size_t)255; return p; };

  uint2* ent_q = (uint2*)alloc(ENT_CAP*8);
  uint2* ent_h = (uint2*)alloc(ENT_CAP*8);
  uint2* ent_m = (uint2*)alloc(ENT_CAP*8);
  uint2* ent_w = (uint2*)alloc(ENT_CAP*8);
  int* rptr_q = (int*)alloc(2001*4);
  int* rptr_h = (int*)alloc(2001*4);
  int* rptr_n = (int*)alloc(2001*4);
  int* cnt_q = (int*)alloc(NROW*4);
  int* cnt_h = (int*)alloc(NROW*4);
  int* cnt_n = (int*)alloc(NROW*4);
  int* ord_q = (int*)alloc(NROW*4);
  int* ord_h = (int*)alloc(NROW*4);
  int* ord_n = (int*)alloc(NROW*4);
  float* rsum_q = (float*)alloc(NROW*4);
  float* rsum_h = (float*)alloc(NROW*4);
  float* rsum_n = (float*)alloc(NROW*4);
  int* deg_n = (int*)alloc(NROW*4);
  float* evq1 = (float*)alloc(NROW*4);
  float* evq2 = (float*)alloc(NROW*4);
  float* evh1 = (float*)alloc(NROW*4);
  float* evh2 = (float*)alloc(NROW*4);
  float* gate3 = (float*)alloc((size_t)NM*3*4);
  h16* xpack = (h16*)alloc((size_t)NT*NM*8*2);
  h16* wp_e0g = (h16*)alloc(11*128*64); h16* wp_e0c = (h16*)alloc(11*64*64);
  h16* wp_e1g = (h16*)alloc(20*128*64); h16* wp_e1c = (h16*)alloc(20*64*64);
  h16* wp_d0gE= (h16*)alloc(11*128*64); h16* wp_d0cE= (h16*)alloc(11*64*64);
  h16* wp_d0gW= (h16*)alloc(20*128*64); h16* wp_d0cW= (h16*)alloc(20*64*64);
  h16* wp_d1g = (h16*)alloc(20*128*64); h16* wp_d1c = (h16*)alloc(20*64*64);
  float* bias2g = (float*)alloc((size_t)NROW*128*4);
  float* bias2c = (float*)alloc((size_t)NROW*64*4);
  const size_t SEG = (size_t)NM*NH*2;
  h16* h0 = (h16*)alloc(SEG);
  h16* h1 = (h16*)alloc(SEG);
  float* ub = (float*)alloc((size_t)NM*NH*4);
  h16* rh = (h16*)alloc(SEG);
  h16* zb = (h16*)alloc(SEG);
  h16* H0Q1=(h16*)alloc(SEG); h16* H0Q2=(h16*)alloc(SEG); h16* H0H1=(h16*)alloc(SEG); h16* H0H2=(h16*)alloc(SEG);
  h16* H1Q1=(h16*)alloc(SEG); h16* H1Q2=(h16*)alloc(SEG); h16* H1H1=(h16*)alloc(SEG); h16* H1H2=(h16*)alloc(SEG);
  h16* RHQ1=(h16*)alloc(SEG); h16* RHQ2=(h16*)alloc(SEG); h16* RHH1=(h16*)alloc(SEG); h16* RHH2=(h16*)alloc(SEG);
  // preamble-only buffers aliased over step-hop buffers (lifetimes disjoint)
  h16* xT   = RHQ1;  h16* Zm = RHQ2;  h16* Zw = RHH1;  h16* ximp = RHH2;
  h16* xq1  = H1Q1;  h16* xq2 = H1Q2; h16* xh1 = H1H1; h16* xh2 = H1H2;

  hipFuncSetAttribute(reinterpret_cast<const void*>(k_hop),
                      hipFuncAttributeMaxDynamicSharedMemorySize, HOPLDS);

  hipMemsetAsync(zb, 0, SEG, stream);
  hipMemsetAsync(h0, 0, SEG, stream);
  hipMemsetAsync(h1, 0, SEG, stream);

  k_count<<<1500,256,0,stream>>>(adj, cnt_q, cnt_h, cnt_n, rsum_q, rsum_h, rsum_n, deg_n);
  k_sort<<<3,1024,0,stream>>>(cnt_q, cnt_h, cnt_n, ord_q, ord_h, ord_n);
  k_scan<<<1,1024,0,stream>>>(cnt_q, cnt_h, cnt_n, rptr_q, rptr_h, rptr_n);
  k_fill<<<1500,256,0,stream>>>(adj, rptr_q, rptr_h, rptr_n, rsum_q, rsum_h, rsum_n, deg_n,
                                ent_q, ent_h, ent_m, ent_w);
  k_evinit<<<8,256,0,stream>>>(rsum_q, rsum_h, evq1, evh1);
  k_matvec<<<500,256,0,stream>>>(rptr_q, ent_q, evq1, evq2);
  k_matvec<<<500,256,0,stream>>>(rptr_h, ent_h, evh1, evh2);
  k_bias2<<<1000,256,0,stream>>>(Wg[2], fcb, evq1, evq2, evh1, evh2, bias2g, 128);
  k_bias2<<<500,256,0,stream>>>(Wc[2], fcb, evq1, evq2, evh1, evh2, bias2c, 64);
  auto wpk = [&](const float* W, h16* dst, int O, int nch, int mode){
    k_wpack<<<(nch*O*32+255)/256,256,0,stream>>>(W, fcw, dst, O, nch, mode);
  };
  wpk(Wg[0], wp_e0g, 128, 11, 0); wpk(Wc[0], wp_e0c, 64, 11, 0);
  wpk(Wg[1], wp_e1g, 128, 20, 1); wpk(Wc[1], wp_e1c, 64, 20, 1);
  wpk(Wg[2], wp_d0gE,128, 11, 0); wpk(Wc[2], wp_d0cE,64, 11, 0);
  wpk(Wg[2], wp_d0gW,128, 20, 2); wpk(Wc[2], wp_d0cW,64, 20, 2);
  wpk(Wg[3], wp_d1g, 128, 20, 1); wpk(Wc[3], wp_d1c, 64, 20, 1);

  k_impute_gate<<<125,256,0,stream>>>(x_enc, gw1, gb1, gw2, gb2, gate3, xT);

  auto hop = [&](HopJob a, HopJob b, HopJob c, HopJob d, int nj, int C, int rsplit){
    int ct = C/32;
    k_hop<<<nj*ct*rsplit, 1024, HOPLDS, stream>>>(a,b,c,d, ct, rsplit, C);
  };
  HopJob JA{xT, rptr_n, ent_m, ord_n, Zm}, JB{xT, rptr_n, ent_w, ord_n, Zw};
  hop(JA, JB, JA, JB, 2, NB*NT, 10);
  k_impute_combine<<<125,256,0,stream>>>(x_enc, Zm, Zw, gate3, ewm, ebm, eww, ebw, ewd, ebd, ximp);
  HopJob X1{ximp, rptr_q, ent_q, ord_q, xq1}, X2{ximp, rptr_h, ent_h, ord_h, xh1};
  hop(X1, X2, X1, X2, 2, NB*NT, 10);
  HopJob X3{xq1, rptr_q, ent_q, ord_q, xq2}, X4{xh1, rptr_h, ent_h, ord_h, xh2};
  hop(X3, X4, X3, X4, 2, NB*NT, 10);
  k_xpack8<<<(NT*NM+255)/256,256,0,stream>>>(ximp, xq1, xq2, xh1, xh2, xpack);

  h16* HSEG0[5] = {h0, H0Q1, H0Q2, H0H1, H0H2};
  h16* HSEG1[5] = {h1, H1Q1, H1Q2, H1H1, H1H2};
  h16* RSEG[5]  = {rh, RHQ1, RHQ2, RHH1, RHH2};
  h16* ZSEG[5]  = {zb, zb, zb, zb, zb};

  auto shapeA = [&](GArgs& A, h16* const* seg, const h16* xpk){
    for (int m=0;m<5;m++) for (int s=0;s<2;s++){ int ch=2*m+s; A.src[ch]=seg[m]; A.rstrideB[ch]=NH*2; A.coffB[ch]=s*64; }
    A.src[10]=xpk; A.rstrideB[10]=16; A.coffB[10]=0; A.nchunks=11; A.xchunk=10;
  };
  auto shapeB = [&](GArgs& A, h16* const* sa, h16* const* sb){
    for (int m=0;m<5;m++) for (int s=0;s<4;s++){ int ch=4*m+s;
      A.src[ch] = (s<2)? sa[m] : sb[m]; A.rstrideB[ch]=NH*2; A.coffB[ch]=(s&1)*64; }
    A.nchunks=20; A.xchunk=-1;
  };
  auto shapeC = [&](GArgs& A, h16* const* segH, h16* const* segX){
    for (int m=0;m<5;m++) for (int s=0;s<2;s++){
      int ch=2*m+s; A.src[ch]=segX[m]; A.rstrideB[ch]=NH*2; A.coffB[ch]=s*64;
      int c2=10+2*m+s; A.src[c2]=segH[m]; A.rstrideB[c2]=NH*2; A.coffB[c2]=s*64; }
    A.nchunks=20; A.xchunk=-1;
  };
  auto common = [&](GArgs& A, const h16* wp, const float* bias, const h16* hb, const float* b2, int t){
    A.wpack=wp; A.bias=bias; A.hbuf=hb; A.rhbuf=rh; A.ubuf=ub; A.hout=(h16*)hb;
    A.bias2=b2; A.fcw=fcw; A.fcb=fcb; A.dout=outp; A.tstep=t;
  };

  for (int phase=0; phase<2; phase++){           // 0 = encoder, 1 = decoder
    int ig = phase? 2 : 0;                       // param index L0
    const h16* wpg0E = phase? wp_d0gE : wp_e0g;
    const h16* wpc0E = phase? wp_d0cE : wp_e0c;
    const h16* wpg1  = phase? wp_d1g  : wp_e1g;
    const h16* wpc1  = phase? wp_d1c  : wp_e1c;
    for (int t=0;t<NT;t++){
      bool wprime = (phase==1 && t>0);
      if (wprime){                               // dec t>=1: h1-hops must precede Gg0 (W' chunks)
        HopJob a{h1, rptr_q, ent_q, ord_q, H1Q1}, b{h1, rptr_h, ent_h, ord_h, H1H1};
        hop(a,b,a,b, 2, NB*NH, 4);
        HopJob c{H1Q1, rptr_q, ent_q, ord_q, H1Q2}, d{H1H1, rptr_h, ent_h, ord_h, H1H2};
        hop(c,d,c,d, 2, NB*NH, 4);
      }
      { // Gg0
        GArgs A{};
        if (wprime) shapeC(A, HSEG0, HSEG1);
        else shapeA(A, (phase==0 && t==0)? ZSEG : HSEG0, xpack + (size_t)((phase==0)? t : 23)*NM*8);
        common(A, wprime? wp_d0gW : wpg0E, bg[ig], h0, bias2g, t);
        if (wprime) k_g<128,1,1,0><<<500,256,0,stream>>>(A);
        else        k_g<128,1,0,0><<<500,256,0,stream>>>(A);
      }
      if (wprime){                               // rh hops only
        HopJob a{rh, rptr_q, ent_q, ord_q, RHQ1}, b{rh, rptr_h, ent_h, ord_h, RHH1};
        hop(a,b,a,b, 2, NB*NH, 4);
        HopJob c{RHQ1, rptr_q, ent_q, ord_q, RHQ2}, d{RHH1, rptr_h, ent_h, ord_h, RHH2};
        hop(c,d,c,d, 2, NB*NH, 4);
      } else {                                   // merged rh + h1prev hops
        HopJob a{rh, rptr_q, ent_q, ord_q, RHQ1}, b{rh, rptr_h, ent_h, ord_h, RHH1};
        HopJob c{h1, rptr_q, ent_q, ord_q, H1Q1}, d{h1, rptr_h, ent_h, ord_h, H1H1};
        hop(a,b,c,d, 4, NB*NH, 2);
        HopJob a2{RHQ1, rptr_q, ent_q, ord_q, RHQ2}, b2{RHH1, rptr_h, ent_h, ord_h, RHH2};
        HopJob c2{H1Q1, rptr_q, ent_q, ord_q, H1Q2}, d2{H1H1, rptr_h, ent_h, ord_h, H1H2};
        hop(a2,b2,c2,d2, 4, NB*NH, 2);
      }
      { // Gc0
        GArgs A{};
        if (wprime) shapeC(A, RSEG, HSEG1);
        else shapeA(A, RSEG, xpack + (size_t)((phase==0)? t : 23)*NM*8);
        common(A, wprime? wp_d0cW : wpc0E, bc[ig], h0, bias2c, t);
        if (wprime) k_g<64,0,1,0><<<500,256,0,stream>>>(A);
        else        k_g<64,0,0,0><<<500,256,0,stream>>>(A);
      }
      { // hops of new h0 (serve L1 now and L0-gate next step)
        HopJob a{h0, rptr_q, ent_q, ord_q, H0Q1}, b{h0, rptr_h, ent_h, ord_h, H0H1};
        hop(a,b,a,b, 2, NB*NH, 4);
        HopJob c{H0Q1, rptr_q, ent_q, ord_q, H0Q2}, d{H0H1, rptr_h, ent_h, ord_h, H0H2};
        hop(c,d,c,d, 2, NB*NH, 4);
      }
      { // Gg1
        GArgs A{};
        shapeB(A, HSEG0, HSEG1);
        common(A, wpg1, bg[ig+1], h1, nullptr, t);
        k_g<128,1,0,0><<<500,256,0,stream>>>(A);
      }
      { // rh1 hops
        HopJob a{rh, rptr_q, ent_q, ord_q, RHQ1}, b{rh, rptr_h, ent_h, ord_h, RHH1};
        hop(a,b,a,b, 2, NB*NH, 4);
        HopJob c{RHQ1, rptr_q, ent_q, ord_q, RHQ2}, d{RHH1, rptr_h, ent_h, ord_h, RHH2};
        hop(c,d,c,d, 2, NB*NH, 4);
      }
      { // Gc1 (+fc output in decoder)
        GArgs A{};
        shapeB(A, HSEG0, RSEG);
        common(A, wpc1, bc[ig+1], h1, nullptr, t);
        if (phase) k_g<64,0,0,1><<<500,256,0,stream>>>(A);
        else       k_g<64,0,0,0><<<500,256,0,stream>>>(A);
      }
    }
  }
}

// Round 5
// 13032.793 us; speedup vs baseline: 1.1901x; 1.1901x over previous
//
#include <hip/hip_runtime.h>

#define NROW 2000
#define NB   16
#define NT   24
#define NH   64
#define NM   (NROW*NB)          // 32000 flat rows (n*16+b)
#define HOPLDS (NROW*64)        // 128000 B dynamic LDS (stride 64: full-bank-coverage rows)
#define ENT_CAP 262144

typedef _Float16 h16;
typedef __attribute__((ext_vector_type(2))) _Float16 h16x2;
typedef __attribute__((ext_vector_type(8))) _Float16 h16x8;
typedef __attribute__((ext_vector_type(4))) float    f32x4;

__device__ __forceinline__ h16x2 bc_h2(unsigned int u){ union{unsigned int u; h16x2 h;} c; c.u=u; return c.h; }

// ---------------------------------------------------------------- CSR build
__global__ __launch_bounds__(256) void k_count(const float* adj, int* cnt_q, int* cnt_h, int* cnt_ns,
    float* rsum_q, float* rsum_h, float* rsum_ns, int* deg_ns){
  int wid = (blockIdx.x*256 + threadIdx.x)>>6;
  int lane = threadIdx.x & 63;
  int kind = wid / NROW, n = wid - kind*NROW;
  int cnt = 0; float sum = 0.f;
  for (int c = lane; c < NROW; c += 64){
    float v = (kind==1) ? adj[(size_t)c*NROW + n] : adj[(size_t)n*NROW + c];
    if (kind==2 && c==n) v = 0.f;
    cnt += (v != 0.f); sum += v;
  }
  for (int off=32; off; off>>=1){ cnt += __shfl_down(cnt,off); sum += __shfl_down(sum,off); }
  if (lane==0){
    int pc = (cnt+7)&~7;                       // pad rows to multiple of 8 entries
    if (kind==0){ cnt_q[n]=pc; rsum_q[n]=sum; }
    else if (kind==1){ cnt_h[n]=pc; rsum_h[n]=sum; }
    else { cnt_ns[n]=pc; rsum_ns[n]=sum; deg_ns[n]=cnt; }
  }
}

__global__ __launch_bounds__(1024) void k_scan(const int* cq, const int* ch, const int* cn,
    int* rq, int* rh, int* rn){
  __shared__ int s0[2048], s1[2048], s2[2048];
  int t = threadIdx.x;
  for (int a=0;a<2;a++){ int i=t+a*1024; s0[i]= i<NROW?cq[i]:0; s1[i]= i<NROW?ch[i]:0; s2[i]= i<NROW?cn[i]:0; }
  __syncthreads();
  for (int off=1; off<2048; off<<=1){
    int v0[2],v1[2],v2[2];
    for (int a=0;a<2;a++){ int i=t+a*1024; v0[a]= i>=off? s0[i-off]:0; v1[a]= i>=off? s1[i-off]:0; v2[a]= i>=off? s2[i-off]:0; }
    __syncthreads();
    for (int a=0;a<2;a++){ int i=t+a*1024; s0[i]+=v0[a]; s1[i]+=v1[a]; s2[i]+=v2[a]; }
    __syncthreads();
  }
  for (int a=0;a<2;a++){ int i=t+a*1024; if (i<=NROW){ rq[i]= i? s0[i-1]:0; rh[i]= i? s1[i-1]:0; rn[i]= i? s2[i-1]:0; } }
}

// degree-bucket counting sort: rows grouped by padded cnt (16-entry bins) so
// same-wave rows in k_hop have ~equal trip counts. Scatter order within a bin
// is atomic-order-dependent but numerics are row-independent -> output exact.
__global__ __launch_bounds__(1024) void k_sort(const int* c0, const int* c1, const int* c2,
                                               int* o0, int* o1, int* o2){
  const int* cnt = blockIdx.x==0 ? c0 : blockIdx.x==1 ? c1 : c2;
  int* order     = blockIdx.x==0 ? o0 : blockIdx.x==1 ? o1 : o2;
  __shared__ int hist[256];
  __shared__ int offs[256];
  int tid = threadIdx.x;
  if (tid < 256) hist[tid] = 0;
  __syncthreads();
  for (int r = tid; r < NROW; r += 1024){
    int b = cnt[r] >> 4; if (b > 255) b = 255;
    atomicAdd(&hist[b], 1);
  }
  __syncthreads();
  if (tid == 0){ int s = 0; for (int i=0;i<256;i++){ offs[i] = s; s += hist[i]; } }
  __syncthreads();
  for (int r = tid; r < NROW; r += 1024){
    int b = cnt[r] >> 4; if (b > 255) b = 255;
    int p = atomicAdd(&offs[b], 1);
    order[p] = r;
  }
}

__device__ __forceinline__ uint2 mk_ent(int c, float a){
  h16 h = (h16)a;
  unsigned short us = __builtin_bit_cast(unsigned short, h);
  return make_uint2((unsigned int)(c*64), (unsigned int)us * 0x10001u);
}

__global__ __launch_bounds__(256) void k_fill(const float* adj, const int* rptr_q, const int* rptr_h, const int* rptr_ns,
    const float* rsum_q, const float* rsum_h, const float* rsum_ns, const int* deg_ns,
    uint2* ent_q, uint2* ent_h, uint2* ent_m, uint2* ent_w){
  int wid = (blockIdx.x*256 + threadIdx.x)>>6;
  int lane = threadIdx.x & 63;
  int kind = wid / NROW, n = wid - kind*NROW;
  const int* rp = (kind==0)?rptr_q:(kind==1)?rptr_h:rptr_ns;
  int p = rp[n], pend = rp[n+1];
  float inv, invm = 0.f;
  if (kind==0){ float d = rsum_q[n]; inv = d!=0.f?1.f/d:0.f; }
  else if (kind==1){ float d = rsum_h[n]; inv = d!=0.f?1.f/d:0.f; }
  else { float d = rsum_ns[n]; inv = d!=0.f?1.f/d:0.f; int dg = deg_ns[n]; invm = 1.f/(float)(dg>1?dg:1); }
  int base = 0;
  unsigned long long below = (1ull<<lane)-1ull;
  for (int c0=0; c0<NROW; c0+=64){
    int c = c0+lane; float v = 0.f;
    if (c < NROW){ v = (kind==1)? adj[(size_t)c*NROW+n] : adj[(size_t)n*NROW+c]; if (kind==2 && c==n) v = 0.f; }
    unsigned long long m = __ballot(v != 0.f);
    if (v != 0.f){
      int pos = p + base + __popcll(m & below);
      if (kind==2){ ent_w[pos] = mk_ent(c, v*inv); ent_m[pos] = mk_ent(c, invm); }
      else if (kind==0) ent_q[pos] = mk_ent(c, v*inv);
      else              ent_h[pos] = mk_ent(c, v*inv);
    }
    base += __popcll(m);
  }
  for (int i = p+base+lane; i < pend; i += 64){
    uint2 z = make_uint2(0u,0u);
    if (kind==2){ ent_w[i]=z; ent_m[i]=z; } else if (kind==0) ent_q[i]=z; else ent_h[i]=z;
  }
}

// ---------------------------------------------------------------- sparse hop (SpMM), LDS-staged
// 1024 threads, 4-lane groups, ds_read_b128, row stride 64B. Degree-sorted row
// order (equal trip counts per wave) + rsplit-interleaved units (block balance).
struct HopJob { const h16* X; const int* rptr; const uint2* ent; const int* order; h16* out; };

__device__ __forceinline__ void proc2(const char* xs, int cl, uint4 p, h16x2 ha[4]){
  union{f32x4 v; h16x2 h[4];} ca, cb;
  ca.v = *(const f32x4*)(xs + p.x + cl);
  cb.v = *(const f32x4*)(xs + p.z + cl);
  h16x2 va = bc_h2(p.y), vb = bc_h2(p.w);
  ha[0] = ca.h[0]*va + ha[0];
  ha[1] = ca.h[1]*va + ha[1];
  ha[2] = ca.h[2]*va + ha[2];
  ha[3] = ca.h[3]*va + ha[3];
  ha[0] = cb.h[0]*vb + ha[0];
  ha[1] = cb.h[1]*vb + ha[1];
  ha[2] = cb.h[2]*vb + ha[2];
  ha[3] = cb.h[3]*vb + ha[3];
}

__global__ __launch_bounds__(1024) void k_hop(HopJob j0, HopJob j1, HopJob j2, HopJob j3,
                                              int coltiles, int rsplit, int C){
  extern __shared__ char xs[];
  int per = coltiles*rsplit;
  int bid = blockIdx.x;
  int jb = bid/per, rem = bid - jb*per;
  int ct = rem/rsplit, rs = rem - ct*rsplit;
  HopJob j = (jb==0)?j0:(jb==1)?j1:(jb==2)?j2:j3;
  int c0 = ct*32;
  int tid = threadIdx.x;
  { // stage X[:, c0..c0+31] fp16 into LDS, row stride 64B (conflict-free writes)
    int r0 = tid>>2, so = tid&3;
    const char* src = (const char*)j.X + (size_t)2*(c0 + so*8);
    char* dst = xs + so*16;
    for (int r = r0; r < NROW; r += 256)
      *(f32x4*)(dst + r*64) = *(const f32x4*)(src + (size_t)2*r*C);
  }
  __syncthreads();
  int lane = tid&63, wv = tid>>6;           // 16 waves
  int g = lane>>2;                          // 16 groups of 4 lanes
  int cl = (lane&3)*16;                     // 16B (8 cols) per lane
  // units: 125 units of 16 sorted rows; block rs takes units gu = rs + k*rsplit
  for (int k = wv; ; k += 16){
    int gu = rs + k*rsplit;
    if (gu >= 125) break;
    int n = j.order[gu*16 + g];
    {
      int p0 = j.rptr[n], cnt = j.rptr[n+1]-p0;
      const uint4* ep4 = (const uint4*)(j.ent + p0);   // 2 entries per uint4
      float f[8] = {0.f,0.f,0.f,0.f,0.f,0.f,0.f,0.f};
      if (cnt > 0){
        uint4 cur[8];
        #pragma unroll
        for (int u2=0;u2<8;u2++) cur[u2] = ep4[u2];    // 16 entries (overread garbage-safe)
        int i = 0;
        for (; i+16 <= cnt; i += 16){
          uint4 nx[8];
          int b = (i>>1)+8;
          #pragma unroll
          for (int u2=0;u2<8;u2++) nx[u2] = ep4[b+u2]; // next 16, issued before compute
          h16x2 ha[4] = {{(_Float16)0.f,(_Float16)0.f},{(_Float16)0.f,(_Float16)0.f},
                         {(_Float16)0.f,(_Float16)0.f},{(_Float16)0.f,(_Float16)0.f}};
          #pragma unroll
          for (int u2=0;u2<8;u2++) proc2(xs, cl, cur[u2], ha);
          f[0] += (float)ha[0][0]; f[1] += (float)ha[0][1];
          f[2] += (float)ha[1][0]; f[3] += (float)ha[1][1];
          f[4] += (float)ha[2][0]; f[5] += (float)ha[2][1];
          f[6] += (float)ha[3][0]; f[7] += (float)ha[3][1];
          #pragma unroll
          for (int u2=0;u2<8;u2++) cur[u2] = nx[u2];
        }
        if (i < cnt){                                   // tail of 8 (cnt % 16 == 8)
          h16x2 ha[4] = {{(_Float16)0.f,(_Float16)0.f},{(_Float16)0.f,(_Float16)0.f},
                         {(_Float16)0.f,(_Float16)0.f},{(_Float16)0.f,(_Float16)0.f}};
          proc2(xs, cl, cur[0], ha);
          proc2(xs, cl, cur[1], ha);
          proc2(xs, cl, cur[2], ha);
          proc2(xs, cl, cur[3], ha);
          f[0] += (float)ha[0][0]; f[1] += (float)ha[0][1];
          f[2] += (float)ha[1][0]; f[3] += (float)ha[1][1];
          f[4] += (float)ha[2][0]; f[5] += (float)ha[2][1];
          f[6] += (float)ha[3][0]; f[7] += (float)ha[3][1];
        }
      }
      alignas(16) h16 ov[8];
      #pragma unroll
      for (int k2=0;k2<8;k2++) ov[k2] = (h16)f[k2];
      *(uint4*)((char*)j.out + (size_t)2*((size_t)n*C + c0) + cl) = *(const uint4*)ov;
    }
  }
}

// ---------------------------------------------------------------- misc small kernels
__global__ void k_evinit(const float* rq, const float* rh, float* eq, float* eh){
  int n = blockIdx.x*256+threadIdx.x; if (n>=NROW) return;
  eq[n] = rq[n]!=0.f?1.f:0.f; eh[n] = rh[n]!=0.f?1.f:0.f;
}

__global__ __launch_bounds__(256) void k_matvec(const int* rptr, const uint2* ent, const float* vin, float* vout){
  int wid = (blockIdx.x*256+threadIdx.x)>>6; int lane = threadIdx.x&63;
  if (wid >= NROW) return;
  int p0 = rptr[wid], p1 = rptr[wid+1];
  float s = 0.f;
  for (int i=p0+lane; i<p1; i+=64){
    uint2 e = ent[i];
    int idx = (int)(e.x>>6);
    h16 hv = __builtin_bit_cast(h16, (unsigned short)(e.y & 0xffffu));
    s += (float)hv * vin[idx];
  }
  for (int off=32; off; off>>=1) s += __shfl_down(s,off);
  if (lane==0) vout[wid] = s;
}

__global__ void k_bias2(const float* W, const float* fcb, const float* e1, const float* e2,
                        const float* e3, const float* e4, float* dst, int O){
  int idx = blockIdx.x*256+threadIdx.x; if (idx >= NROW*O) return;
  int n = idx/O, o = idx - n*O;
  float v = W[o] + e1[n]*W[(size_t)65*O+o] + e2[n]*W[(size_t)130*O+o]
                 + e3[n]*W[(size_t)195*O+o] + e4[n]*W[(size_t)260*O+o];
  dst[idx] = fcb[0]*v;
}

// wpack: fp16 transposed W chunks [ch][O][32] for MFMA B-operand
__global__ void k_wpack(const float* W, const float* fcw, h16* dst, int O, int nch, int mode){
  int idx = blockIdx.x*256+threadIdx.x; if (idx >= nch*O*32) return;
  int k = idx&31; int o = (idx>>5)%O; int ch = idx/(O*32);
  float v = 0.f;
  if (mode==0){            // L0 enc-style: ch0-9 h-rows, ch10 x-rows
    if (ch < 10){ int m = ch>>1, j = (ch&1)*32 + k; v = W[(size_t)(m*65+1+j)*O + o]; }
    else if (k < 5) v = W[(size_t)(k*65)*O + o];
  } else if (mode==1){     // L1: ch 4m+s, j = (ch&3)*32+k
    int m = ch>>2, j = (ch&3)*32 + k; v = W[(size_t)(m*128+j)*O + o];
  } else {                 // L0 dec W'-style: ch0-9 = fcw[j]*W[m*65,o], ch10-19 h-rows
    if (ch < 10){ int m = ch>>1, j = (ch&1)*32 + k; v = fcw[j]*W[(size_t)(m*65)*O + o]; }
    else { int c2 = ch-10; int m = c2>>1, j = (c2&1)*32 + k; v = W[(size_t)(m*65+1+j)*O + o]; }
  }
  dst[(size_t)(ch*O + o)*32 + k] = (h16)v;
}

// ---------------------------------------------------------------- imputation
__global__ __launch_bounds__(256) void k_impute_gate(const float* x_enc, const float* gw1, const float* gb1,
    const float* gw2, const float* gb2, float* gate3, h16* xT){
  int tid = blockIdx.x*256+threadIdx.x; if (tid >= NM) return;
  int b = tid / NROW, n = tid - b*NROW;
  float x24[NT];
  #pragma unroll
  for (int t=0;t<NT;t++) x24[t] = x_enc[((size_t)b*NT+t)*NROW + n];
  float acc[NH];
  #pragma unroll
  for (int h=0;h<NH;h++) acc[h] = gb1[h];
  for (int t=0;t<NT;t++){
    float xv = x24[t];
    #pragma unroll
    for (int h=0;h<NH;h++) acc[h] = fmaf(xv, gw1[t*NH+h], acc[h]);
  }
  #pragma unroll
  for (int h=0;h<NH;h++) acc[h] = fmaxf(acc[h], 0.f);
  float lg[3];
  #pragma unroll
  for (int e=0;e<3;e++){
    float s = gb2[e];
    #pragma unroll
    for (int h=0;h<NH;h++) s = fmaf(acc[h], gw2[h*3+e], s);
    lg[e] = s;
  }
  int i0 = 0; if (lg[1] > lg[0]) i0 = 1; if (lg[2] > lg[i0]) i0 = 2;
  int i1 = (i0==0)?1:0;
  for (int e=0;e<3;e++) if (e!=i0 && e!=i1 && lg[e] > lg[i1]) i1 = e;
  float w1 = expf(lg[i1]-lg[i0]);
  float s = 1.f + w1;
  float g[3] = {0.f,0.f,0.f};
  g[i0] = 1.f/s; g[i1] = w1/s;
  gate3[tid*3+0]=g[0]; gate3[tid*3+1]=g[1]; gate3[tid*3+2]=g[2];
  h16* xp = xT + ((size_t)n*NB + b)*NT;
  #pragma unroll
  for (int t=0;t<NT;t++) xp[t] = (h16)x24[t];
}

__global__ __launch_bounds__(256) void k_impute_combine(const float* x_enc, const h16* Zm, const h16* Zw,
    const float* gate3, const float* ewm, const float* ebm, const float* eww, const float* ebw,
    const float* ewd, const float* ebd, h16* ximp){
  int tid = blockIdx.x*256+threadIdx.x; if (tid >= NM) return;
  int b = tid / NROW, n = tid - b*NROW;
  float x24[NT], zm[NT], zw[NT];
  const h16* zp1 = Zm + ((size_t)n*NB+b)*NT;
  const h16* zp2 = Zw + ((size_t)n*NB+b)*NT;
  #pragma unroll
  for (int t=0;t<NT;t++){ x24[t] = x_enc[((size_t)b*NT+t)*NROW + n]; zm[t]=(float)zp1[t]; zw[t]=(float)zp2[t]; }
  float g0=gate3[tid*3], g1=gate3[tid*3+1], g2=gate3[tid*3+2];
  h16* op = ximp + ((size_t)n*NB+b)*NT;
  for (int t=0;t<NT;t++){
    float am=ebm[t], aw=ebw[t], ad=ebd[t];
    #pragma unroll
    for (int ss=0;ss<NT;ss++){ am = fmaf(zm[ss], ewm[ss*NT+t], am); aw = fmaf(zw[ss], eww[ss*NT+t], aw); ad = fmaf(zw[ss], ewd[ss*NT+t], ad); }
    float comb = g0*am + g1*aw + g2*ad;
    op[t] = (h16)((x24[t]==0.f)? comb : x24[t]);
  }
}

__global__ void k_xpack8(const h16* ximp, const h16* xq1, const h16* xq2, const h16* xh1, const h16* xh2, h16* xp){
  int idx = blockIdx.x*256+threadIdx.x; if (idx >= NT*NM) return;
  int t = idx/NM, r = idx - t*NM;
  size_t s = (size_t)r*NT + t;
  alignas(16) h16 v[8] = { ximp[s], xq1[s], xq2[s], xh1[s], xh2[s], (h16)0.f,(h16)0.f,(h16)0.f };
  *(uint4*)(xp + ((size_t)t*NM + r)*8) = *(const uint4*)v;
}

// ---------------------------------------------------------------- MFMA combine GEMM + fused cell epilogue
// R3 structure: 64-row tiles, LDS-staged, one-chunk-ahead reg prefetch, 500 blocks.
struct GArgs {
  const h16* src[20];
  int rstrideB[20];
  int coffB[20];
  const h16* wpack;
  const float* bias;
  const h16* hbuf;
  h16* rhbuf;
  float* ubuf;
  h16* hout;
  const float* bias2;
  const float* fcw;
  const float* fcb;
  float* dout;
  int tstep;
  int nchunks;
  int xchunk;
};

template<int O, int GATE, int BIAS2, int FCOUT>
__global__ __launch_bounds__(256) void k_g(GArgs a){
  __shared__ h16 As[64*40];
  __shared__ h16 Bs[O*40];
  const int tid = threadIdx.x;
  const int lane = tid&63, wv = tid>>6;
  const int l15 = lane&15, l4 = lane>>4;
  const int mbase = blockIdx.x*64;
  f32x4 acc[O/16];
  #pragma unroll
  for (int cf=0;cf<O/16;cf++) acc[cf] = (f32x4){0.f,0.f,0.f,0.f};

  f32x4 ra, rb[O/64 > 0 ? O/64 : 1];
  const f32x4 vz = (f32x4){0.f,0.f,0.f,0.f};
  const int r_ = tid>>2, q_ = tid&3;
  auto loadA = [&](int ch){
    const char* sp = (const char*)a.src[ch] + a.coffB[ch] + (size_t)mbase*a.rstrideB[ch];
    if (ch == a.xchunk){
      ra = q_ ? vz : *(const f32x4*)(sp + (size_t)r_*16);
    } else {
      int rs = a.rstrideB[ch];
      ra = *(const f32x4*)(sp + (size_t)r_*rs + q_*16);
    }
    const char* wp = (const char*)a.wpack + (size_t)ch*O*64;
    #pragma unroll
    for (int ps=0; ps<O/64; ps++){
      int flat = ps*256+tid;
      rb[ps] = *(const f32x4*)(wp + (size_t)flat*16);
    }
  };
  auto writeA = [&](int ch){
    *(f32x4*)((char*)As + r_*80 + q_*16) = ra;
    #pragma unroll
    for (int ps=0; ps<O/64; ps++){
      int flat = ps*256+tid; int r = flat>>2, q = flat&3;
      *(f32x4*)((char*)Bs + r*80 + q*16) = rb[ps];
    }
  };

  loadA(0);
  for (int ch=0; ch<a.nchunks; ch++){
    writeA(ch);
    __syncthreads();
    if (ch+1 < a.nchunks) loadA(ch+1);     // issue next-chunk loads; latency hides under MFMA
    h16x8 a0 = *(const h16x8*)((const char*)As + (wv*16 + l15)*80 + l4*16);
    #pragma unroll
    for (int cf=0; cf<O/16; cf++){
      h16x8 bfr = *(const h16x8*)((const char*)Bs + (cf*16 + l15)*80 + l4*16);
      acc[cf] = __builtin_amdgcn_mfma_f32_16x16x32_f16(a0, bfr, acc[cf], 0,0,0);
    }
    __syncthreads();
  }
  float fcp[4] = {0.f,0.f,0.f,0.f};
  #pragma unroll
  for (int cf=0; cf<O/16; cf++){
    #pragma unroll
    for (int i=0;i<4;i++){
      int row = mbase + wv*16 + l4*4 + i;
      int col = cf*16 + l15;
      float v = acc[cf][i] + a.bias[col];
      if (BIAS2) v += a.bias2[(size_t)(row>>4)*O + col];
      if (GATE){
        float sg = 1.f/(1.f+expf(-v));
        if (cf*16 < NH){                              // r half
          float hv = (float)a.hbuf[(size_t)row*NH + col];
          a.rhbuf[(size_t)row*NH + col] = (h16)(sg*hv);
        } else {                                      // u half
          a.ubuf[(size_t)row*NH + (col-NH)] = sg;
        }
      } else {
        float cc = tanhf(v);
        float u  = a.ubuf[(size_t)row*NH + col];
        float hv = (float)a.hbuf[(size_t)row*NH + col];
        float hn = u*hv + (1.f-u)*cc;
        a.hout[(size_t)row*NH + col] = (h16)hn;
        if (FCOUT) fcp[i] += hn * a.fcw[col];
      }
    }
  }
  if (FCOUT){
    #pragma unroll
    for (int k=0;k<4;k++){
      float s = fcp[k];
      s += __shfl_xor(s,1); s += __shfl_xor(s,2); s += __shfl_xor(s,4); s += __shfl_xor(s,8);
      if (l15==0){
        int row = mbase + wv*16 + l4*4 + k;
        int n = row>>4, b = row&15;
        a.dout[(size_t)b*(NT*NROW) + (size_t)a.tstep*NROW + n] = s + a.fcb[0];
      }
    }
  }
}

// ---------------------------------------------------------------- host
extern "C" void kernel_launch(void* const* d_in, const int* in_sizes, int n_in,
                              void* d_out, int out_size, void* d_ws, size_t ws_size,
                              hipStream_t stream)
{
  const float* adj   = (const float*)d_in[0];
  const float* x_enc = (const float*)d_in[1];
  const float* gw1   = (const float*)d_in[3];
  const float* gb1   = (const float*)d_in[4];
  const float* gw2   = (const float*)d_in[5];
  const float* gb2   = (const float*)d_in[6];
  const float* ewm   = (const float*)d_in[7];
  const float* ebm   = (const float*)d_in[8];
  const float* eww   = (const float*)d_in[9];
  const float* ebw   = (const float*)d_in[10];
  const float* ewd   = (const float*)d_in[11];
  const float* ebd   = (const float*)d_in[12];
  const float* Wg[4] = {(const float*)d_in[13],(const float*)d_in[17],(const float*)d_in[21],(const float*)d_in[25]};
  const float* bg[4] = {(const float*)d_in[14],(const float*)d_in[18],(const float*)d_in[22],(const float*)d_in[26]};
  const float* Wc[4] = {(const float*)d_in[15],(const float*)d_in[19],(const float*)d_in[23],(const float*)d_in[27]};
  const float* bc[4] = {(const float*)d_in[16],(const float*)d_in[20],(const float*)d_in[24],(const float*)d_in[28]};
  const float* fcw   = (const float*)d_in[29];
  const float* fcb   = (const float*)d_in[30];
  float* outp = (float*)d_out;
  (void)in_sizes; (void)n_in; (void)out_size; (void)ws_size;

  char* base = (char*)d_ws;
  size_t off = 0;
  auto alloc = [&](size_t sz)->char*{ char* p = base + off; off += (sz + 255) & ~(size_t)255; return p; };

  uint2* ent_q = (uint2*)alloc(ENT_CAP*8);
  uint2* ent_h = (uint2*)alloc(ENT_CAP*8);
  uint2* ent_m = (uint2*)alloc(ENT_CAP*8);
  uint2* ent_w = (uint2*)alloc(ENT_CAP*8);
  int* rptr_q = (int*)alloc(2001*4);
  int* rptr_h = (int*)alloc(2001*4);
  int* rptr_n = (int*)alloc(2001*4);
  int* cnt_q = (int*)alloc(NROW*4);
  int* cnt_h = (int*)alloc(NROW*4);
  int* cnt_n = (int*)alloc(NROW*4);
  int* ord_q = (int*)alloc(NROW*4);
  int* ord_h = (int*)alloc(NROW*4);
  int* ord_n = (int*)alloc(NROW*4);
  float* rsum_q = (float*)alloc(NROW*4);
  float* rsum_h = (float*)alloc(NROW*4);
  float* rsum_n = (float*)alloc(NROW*4);
  int* deg_n = (int*)alloc(NROW*4);
  float* evq1 = (float*)alloc(NROW*4);
  float* evq2 = (float*)alloc(NROW*4);
  float* evh1 = (float*)alloc(NROW*4);
  float* evh2 = (float*)alloc(NROW*4);
  float* gate3 = (float*)alloc((size_t)NM*3*4);
  h16* xpack = (h16*)alloc((size_t)NT*NM*8*2);
  h16* wp_e0g = (h16*)alloc(11*128*64); h16* wp_e0c = (h16*)alloc(11*64*64);
  h16* wp_e1g = (h16*)alloc(20*128*64); h16* wp_e1c = (h16*)alloc(20*64*64);
  h16* wp_d0gE= (h16*)alloc(11*128*64); h16* wp_d0cE= (h16*)alloc(11*64*64);
  h16* wp_d0gW= (h16*)alloc(20*128*64); h16* wp_d0cW= (h16*)alloc(20*64*64);
  h16* wp_d1g = (h16*)alloc(20*128*64); h16* wp_d1c = (h16*)alloc(20*64*64);
  float* bias2g = (float*)alloc((size_t)NROW*128*4);
  float* bias2c = (float*)alloc((size_t)NROW*64*4);
  const size_t SEG = (size_t)NM*NH*2;
  h16* h0 = (h16*)alloc(SEG);
  h16* h1 = (h16*)alloc(SEG);
  float* ub = (float*)alloc((size_t)NM*NH*4);
  h16* rh = (h16*)alloc(SEG);
  h16* zb = (h16*)alloc(SEG);
  h16* H0Q1=(h16*)alloc(SEG); h16* H0Q2=(h16*)alloc(SEG); h16* H0H1=(h16*)alloc(SEG); h16* H0H2=(h16*)alloc(SEG);
  h16* H1Q1=(h16*)alloc(SEG); h16* H1Q2=(h16*)alloc(SEG); h16* H1H1=(h16*)alloc(SEG); h16* H1H2=(h16*)alloc(SEG);
  h16* RHQ1=(h16*)alloc(SEG); h16* RHQ2=(h16*)alloc(SEG); h16* RHH1=(h16*)alloc(SEG); h16* RHH2=(h16*)alloc(SEG);
  // preamble-only buffers aliased over step-hop buffers (lifetimes disjoint)
  h16* xT   = RHQ1;  h16* Zm = RHQ2;  h16* Zw = RHH1;  h16* ximp = RHH2;
  h16* xq1  = H1Q1;  h16* xq2 = H1Q2; h16* xh1 = H1H1; h16* xh2 = H1H2;

  hipFuncSetAttribute(reinterpret_cast<const void*>(k_hop),
                      hipFuncAttributeMaxDynamicSharedMemorySize, HOPLDS);

  hipMemsetAsync(zb, 0, SEG, stream);
  hipMemsetAsync(h0, 0, SEG, stream);
  hipMemsetAsync(h1, 0, SEG, stream);

  k_count<<<1500,256,0,stream>>>(adj, cnt_q, cnt_h, cnt_n, rsum_q, rsum_h, rsum_n, deg_n);
  k_sort<<<3,1024,0,stream>>>(cnt_q, cnt_h, cnt_n, ord_q, ord_h, ord_n);
  k_scan<<<1,1024,0,stream>>>(cnt_q, cnt_h, cnt_n, rptr_q, rptr_h, rptr_n);
  k_fill<<<1500,256,0,stream>>>(adj, rptr_q, rptr_h, rptr_n, rsum_q, rsum_h, rsum_n, deg_n,
                                ent_q, ent_h, ent_m, ent_w);
  k_evinit<<<8,256,0,stream>>>(rsum_q, rsum_h, evq1, evh1);
  k_matvec<<<500,256,0,stream>>>(rptr_q, ent_q, evq1, evq2);
  k_matvec<<<500,256,0,stream>>>(rptr_h, ent_h, evh1, evh2);
  k_bias2<<<1000,256,0,stream>>>(Wg[2], fcb, evq1, evq2, evh1, evh2, bias2g, 128);
  k_bias2<<<500,256,0,stream>>>(Wc[2], fcb, evq1, evq2, evh1, evh2, bias2c, 64);
  auto wpk = [&](const float* W, h16* dst, int O, int nch, int mode){
    k_wpack<<<(nch*O*32+255)/256,256,0,stream>>>(W, fcw, dst, O, nch, mode);
  };
  wpk(Wg[0], wp_e0g, 128, 11, 0); wpk(Wc[0], wp_e0c, 64, 11, 0);
  wpk(Wg[1], wp_e1g, 128, 20, 1); wpk(Wc[1], wp_e1c, 64, 20, 1);
  wpk(Wg[2], wp_d0gE,128, 11, 0); wpk(Wc[2], wp_d0cE,64, 11, 0);
  wpk(Wg[2], wp_d0gW,128, 20, 2); wpk(Wc[2], wp_d0cW,64, 20, 2);
  wpk(Wg[3], wp_d1g, 128, 20, 1); wpk(Wc[3], wp_d1c, 64, 20, 1);

  k_impute_gate<<<125,256,0,stream>>>(x_enc, gw1, gb1, gw2, gb2, gate3, xT);

  auto hop = [&](HopJob a, HopJob b, HopJob c, HopJob d, int nj, int C, int rsplit){
    int ct = C/32;
    k_hop<<<nj*ct*rsplit, 1024, HOPLDS, stream>>>(a,b,c,d, ct, rsplit, C);
  };
  HopJob JA{xT, rptr_n, ent_m, ord_n, Zm}, JB{xT, rptr_n, ent_w, ord_n, Zw};
  hop(JA, JB, JA, JB, 2, NB*NT, 10);
  k_impute_combine<<<125,256,0,stream>>>(x_enc, Zm, Zw, gate3, ewm, ebm, eww, ebw, ewd, ebd, ximp);
  HopJob X1{ximp, rptr_q, ent_q, ord_q, xq1}, X2{ximp, rptr_h, ent_h, ord_h, xh1};
  hop(X1, X2, X1, X2, 2, NB*NT, 10);
  HopJob X3{xq1, rptr_q, ent_q, ord_q, xq2}, X4{xh1, rptr_h, ent_h, ord_h, xh2};
  hop(X3, X4, X3, X4, 2, NB*NT, 10);
  k_xpack8<<<(NT*NM+255)/256,256,0,stream>>>(ximp, xq1, xq2, xh1, xh2, xpack);

  h16* HSEG0[5] = {h0, H0Q1, H0Q2, H0H1, H0H2};
  h16* HSEG1[5] = {h1, H1Q1, H1Q2, H1H1, H1H2};
  h16* RSEG[5]  = {rh, RHQ1, RHQ2, RHH1, RHH2};
  h16* ZSEG[5]  = {zb, zb, zb, zb, zb};

  auto shapeA = [&](GArgs& A, h16* const* seg, const h16* xpk){
    for (int m=0;m<5;m++) for (int s=0;s<2;s++){ int ch=2*m+s; A.src[ch]=seg[m]; A.rstrideB[ch]=NH*2; A.coffB[ch]=s*64; }
    A.src[10]=xpk; A.rstrideB[10]=16; A.coffB[10]=0; A.nchunks=11; A.xchunk=10;
  };
  auto shapeB = [&](GArgs& A, h16* const* sa, h16* const* sb){
    for (int m=0;m<5;m++) for (int s=0;s<4;s++){ int ch=4*m+s;
      A.src[ch] = (s<2)? sa[m] : sb[m]; A.rstrideB[ch]=NH*2; A.coffB[ch]=(s&1)*64; }
    A.nchunks=20; A.xchunk=-1;
  };
  auto shapeC = [&](GArgs& A, h16* const* segH, h16* const* segX){
    for (int m=0;m<5;m++) for (int s=0;s<2;s++){
      int ch=2*m+s; A.src[ch]=segX[m]; A.rstrideB[ch]=NH*2; A.coffB[ch]=s*64;
      int c2=10+2*m+s; A.src[c2]=segH[m]; A.rstrideB[c2]=NH*2; A.coffB[c2]=s*64; }
    A.nchunks=20; A.xchunk=-1;
  };
  auto common = [&](GArgs& A, const h16* wp, const float* bias, const h16* hb, const float* b2, int t){
    A.wpack=wp; A.bias=bias; A.hbuf=hb; A.rhbuf=rh; A.ubuf=ub; A.hout=(h16*)hb;
    A.bias2=b2; A.fcw=fcw; A.fcb=fcb; A.dout=outp; A.tstep=t;
  };

  for (int phase=0; phase<2; phase++){           // 0 = encoder, 1 = decoder
    int ig = phase? 2 : 0;                       // param index L0
    const h16* wpg0E = phase? wp_d0gE : wp_e0g;
    const h16* wpc0E = phase? wp_d0cE : wp_e0c;
    const h16* wpg1  = phase? wp_d1g  : wp_e1g;
    const h16* wpc1  = phase? wp_d1c  : wp_e1c;
    for (int t=0;t<NT;t++){
      bool wprime = (phase==1 && t>0);
      if (wprime){                               // dec t>=1: h1-hops must precede Gg0 (W' chunks)
        HopJob a{h1, rptr_q, ent_q, ord_q, H1Q1}, b{h1, rptr_h, ent_h, ord_h, H1H1};
        hop(a,b,a,b, 2, NB*NH, 4);
        HopJob c{H1Q1, rptr_q, ent_q, ord_q, H1Q2}, d{H1H1, rptr_h, ent_h, ord_h, H1H2};
        hop(c,d,c,d, 2, NB*NH, 4);
      }
      { // Gg0
        GArgs A{};
        if (wprime) shapeC(A, HSEG0, HSEG1);
        else shapeA(A, (phase==0 && t==0)? ZSEG : HSEG0, xpack + (size_t)((phase==0)? t : 23)*NM*8);
        common(A, wprime? wp_d0gW : wpg0E, bg[ig], h0, bias2g, t);
        if (wprime) k_g<128,1,1,0><<<500,256,0,stream>>>(A);
        else        k_g<128,1,0,0><<<500,256,0,stream>>>(A);
      }
      if (wprime){                               // rh hops only
        HopJob a{rh, rptr_q, ent_q, ord_q, RHQ1}, b{rh, rptr_h, ent_h, ord_h, RHH1};
        hop(a,b,a,b, 2, NB*NH, 4);
        HopJob c{RHQ1, rptr_q, ent_q, ord_q, RHQ2}, d{RHH1, rptr_h, ent_h, ord_h, RHH2};
        hop(c,d,c,d, 2, NB*NH, 4);
      } else {                                   // merged rh + h1prev hops
        HopJob a{rh, rptr_q, ent_q, ord_q, RHQ1}, b{rh, rptr_h, ent_h, ord_h, RHH1};
        HopJob c{h1, rptr_q, ent_q, ord_q, H1Q1}, d{h1, rptr_h, ent_h, ord_h, H1H1};
        hop(a,b,c,d, 4, NB*NH, 2);
        HopJob a2{RHQ1, rptr_q, ent_q, ord_q, RHQ2}, b2{RHH1, rptr_h, ent_h, ord_h, RHH2};
        HopJob c2{H1Q1, rptr_q, ent_q, ord_q, H1Q2}, d2{H1H1, rptr_h, ent_h, ord_h, H1H2};
        hop(a2,b2,c2,d2, 4, NB*NH, 2);
      }
      { // Gc0
        GArgs A{};
        if (wprime) shapeC(A, RSEG, HSEG1);
        else shapeA(A, RSEG, xpack + (size_t)((phase==0)? t : 23)*NM*8);
        common(A, wprime? wp_d0cW : wpc0E, bc[ig], h0, bias2c, t);
        if (wprime) k_g<64,0,1,0><<<500,256,0,stream>>>(A);
        else        k_g<64,0,0,0><<<500,256,0,stream>>>(A);
      }
      { // hops of new h0 (serve L1 now and L0-gate next step)
        HopJob a{h0, rptr_q, ent_q, ord_q, H0Q1}, b{h0, rptr_h, ent_h, ord_h, H0H1};
        hop(a,b,a,b, 2, NB*NH, 4);
        HopJob c{H0Q1, rptr_q, ent_q, ord_q, H0Q2}, d{H0H1, rptr_h, ent_h, ord_h, H0H2};
        hop(c,d,c,d, 2, NB*NH, 4);
      }
      { // Gg1
        GArgs A{};
        shapeB(A, HSEG0, HSEG1);
        common(A, wpg1, bg[ig+1], h1, nullptr, t);
        k_g<128,1,0,0><<<500,256,0,stream>>>(A);
      }
      { // rh1 hops
        HopJob a{rh, rptr_q, ent_q, ord_q, RHQ1}, b{rh, rptr_h, ent_h, ord_h, RHH1};
        hop(a,b,a,b, 2, NB*NH, 4);
        HopJob c{RHQ1, rptr_q, ent_q, ord_q, RHQ2}, d{RHH1, rptr_h, ent_h, ord_h, RHH2};
        hop(c,d,c,d, 2, NB*NH, 4);
      }
      { // Gc1 (+fc output in decoder)
        GArgs A{};
        shapeB(A, HSEG0, RSEG);
        common(A, wpc1, bc[ig+1], h1, nullptr, t);
        if (phase) k_g<64,0,0,1><<<500,256,0,stream>>>(A);
        else       k_g<64,0,0,0><<<500,256,0,stream>>>(A);
      }
    }
  }
}